// Round 1
// baseline (731.427 us; speedup 1.0000x reference)
//
#include <hip/hip_runtime.h>
#include <math.h>

#define NB  8     // batch
#define DM  192   // D_MODEL
#define DH  192   // D_HALF
#define DI  384   // D_INNER
#define DS  128   // D_STATE
#define DTR 12    // DT_RANK
#define XR  268   // DT_RANK + 2*D_STATE
#define L   1024  // H*W

// ---------------------------------------------------------------------------
// xz[b][j][l] = sum_c serp(hid)[b][c][l] * W_in[j][c]
// lane = l (coalesced reads/writes), 4 j-outputs per thread.
__global__ void k_gemm_in(const float* __restrict__ hid,
                          const float* __restrict__ Win,
                          float* __restrict__ xz) {
  const int lane = threadIdx.x;          // 0..63
  const int ty   = threadIdx.y;          // 0..3
  const int l    = blockIdx.x * 64 + lane;
  const int j0   = blockIdx.y * 16 + ty * 4;
  const int b    = blockIdx.z;
  const int h = l >> 5, w = l & 31;
  const int wsp = (h & 1) ? (31 - w) : w;          // serpentine read
  const float* hb = hid + ((size_t)b * DM) * L + h * 32 + wsp;
  const float* w0 = Win + (size_t)(j0 + 0) * DM;
  const float* w1 = Win + (size_t)(j0 + 1) * DM;
  const float* w2 = Win + (size_t)(j0 + 2) * DM;
  const float* w3 = Win + (size_t)(j0 + 3) * DM;
  float a0 = 0.f, a1 = 0.f, a2 = 0.f, a3 = 0.f;
#pragma unroll 8
  for (int c = 0; c < DM; ++c) {
    float xv = hb[(size_t)c * L];
    a0 = fmaf(w0[c], xv, a0);
    a1 = fmaf(w1[c], xv, a1);
    a2 = fmaf(w2[c], xv, a2);
    a3 = fmaf(w3[c], xv, a3);
  }
  float* o = xz + ((size_t)b * DI + j0) * L + l;
  o[0]     = a0;
  o[L]     = a1;
  o[2 * L] = a2;
  o[3 * L] = a3;
}

// ---------------------------------------------------------------------------
// causal depthwise conv (k=4) + SiLU for both halves.
// part 0: x half -> u buffer.  part 1: z half -> ycat rows 192..383.
__global__ void k_conv_silu(const float* __restrict__ xz,
                            const float* __restrict__ cwx,
                            const float* __restrict__ cwz,
                            float* __restrict__ u,
                            float* __restrict__ ycat) {
  int idx = blockIdx.x * blockDim.x + threadIdx.x;
  const int per = NB * DH * L;
  int part = idx / per;
  int rem  = idx - part * per;
  int l  = rem & (L - 1);
  int bd = rem >> 10;          // b*DH + d
  int d  = bd % DH;
  int b  = bd / DH;
  const float* cw = (part ? cwz : cwx) + d * 4;
  float w0 = cw[0], w1 = cw[1], w2 = cw[2], w3 = cw[3];
  const float* src = xz + ((size_t)b * DI + (part ? DH + d : d)) * L;
  float s = w3 * src[l];
  if (l >= 1) s = fmaf(w2, src[l - 1], s);
  if (l >= 2) s = fmaf(w1, src[l - 2], s);
  if (l >= 3) s = fmaf(w0, src[l - 3], s);
  float y = s / (1.f + __expf(-s));    // silu
  if (part) ycat[((size_t)b * DI + DH + d) * L + l] = y;
  else      u[(size_t)bd * L + l] = y;
}

// ---------------------------------------------------------------------------
// x_dbl[b][l][r] = sum_d u[b][d][l] * W_xproj[r][d]   (r = 0..267)
// Stored l-major-row so the scan's per-step B/C reads are coalesced.
__global__ void k_gemm_xproj(const float* __restrict__ u,
                             const float* __restrict__ Wx,
                             float* __restrict__ xdbl) {
  const int lane = threadIdx.x;
  const int ty   = threadIdx.y;
  const int l    = blockIdx.x * 64 + lane;
  const int r0   = blockIdx.y * 16 + ty * 4;
  const int b    = blockIdx.z;
  const float* ub = u + ((size_t)b * DH) * L + l;
  const int rr0 = min(r0 + 0, XR - 1);
  const int rr1 = min(r0 + 1, XR - 1);
  const int rr2 = min(r0 + 2, XR - 1);
  const int rr3 = min(r0 + 3, XR - 1);
  const float* w0 = Wx + (size_t)rr0 * DH;
  const float* w1 = Wx + (size_t)rr1 * DH;
  const float* w2 = Wx + (size_t)rr2 * DH;
  const float* w3 = Wx + (size_t)rr3 * DH;
  float a0 = 0.f, a1 = 0.f, a2 = 0.f, a3 = 0.f;
#pragma unroll 8
  for (int c = 0; c < DH; ++c) {
    float xv = ub[(size_t)c * L];
    a0 = fmaf(w0[c], xv, a0);
    a1 = fmaf(w1[c], xv, a1);
    a2 = fmaf(w2[c], xv, a2);
    a3 = fmaf(w3[c], xv, a3);
  }
  float* o = xdbl + ((size_t)b * L + l) * XR;
  if (r0 + 0 < XR) o[r0 + 0] = a0;
  if (r0 + 1 < XR) o[r0 + 1] = a1;
  if (r0 + 2 < XR) o[r0 + 2] = a2;
  if (r0 + 3 < XR) o[r0 + 3] = a3;
}

// ---------------------------------------------------------------------------
// delta[b][d][l] = softplus( sum_r W_dt[d][r]*x_dbl[b][l][r] + 2*b_dt[d] )
// (reference adds b_dt twice)
__global__ void k_delta(const float* __restrict__ xdbl,
                        const float* __restrict__ Wdt,
                        const float* __restrict__ bdt,
                        float* __restrict__ delta) {
  int idx = blockIdx.x * blockDim.x + threadIdx.x;  // (b*DH+d)*L + l
  int l  = idx & (L - 1);
  int bd = idx >> 10;
  int d  = bd % DH;
  int b  = bd / DH;
  const float* xd = xdbl + ((size_t)b * L + l) * XR;
  const float* wd = Wdt + d * DTR;
  float s = 2.f * bdt[d];
#pragma unroll
  for (int r = 0; r < DTR; ++r) s = fmaf(wd[r], xd[r], s);
  float dl = (s > 20.f) ? s : log1pf(__expf(s));
  delta[(size_t)idx] = dl;
}

// ---------------------------------------------------------------------------
// selective scan: one wave per (b,d); lane holds states n=lane and n=lane+64.
__global__ void __launch_bounds__(64) k_scan(const float* __restrict__ xdbl,
                                             const float* __restrict__ delta,
                                             const float* __restrict__ u,
                                             const float* __restrict__ Alog,
                                             const float* __restrict__ Dp,
                                             float* __restrict__ ycat) {
  const int bd   = blockIdx.x;      // b*DH + d
  const int b    = bd / DH;
  const int d    = bd % DH;
  const int lane = threadIdx.x;
  const float a1 = -__expf(Alog[d * DS + lane]);
  const float a2 = -__expf(Alog[d * DS + 64 + lane]);
  const float* xrow = xdbl + (size_t)b * L * XR;
  const float* drow = delta + (size_t)bd * L;
  const float* urow = u + (size_t)bd * L;
  const float Dd = Dp[d];
  float* yrow = ycat + ((size_t)b * DI + d) * L;
  float h1 = 0.f, h2 = 0.f;
  for (int t = 0; t < L; ++t) {
    const float* xd = xrow + (size_t)t * XR;
    float Bv1 = xd[DTR + lane];
    float Bv2 = xd[DTR + 64 + lane];
    float Cv1 = xd[DTR + DS + lane];
    float Cv2 = xd[DTR + DS + 64 + lane];
    float dt = drow[t];
    float ut = urow[t];
    float du = dt * ut;
    h1 = fmaf(__expf(dt * a1), h1, du * Bv1);
    h2 = fmaf(__expf(dt * a2), h2, du * Bv2);
    float p = fmaf(h2, Cv2, h1 * Cv1);
#pragma unroll
    for (int m = 32; m; m >>= 1) p += __shfl_xor(p, m, 64);
    if (lane == 0) yrow[t] = fmaf(Dd, ut, p);
  }
}

// ---------------------------------------------------------------------------
// out[b][c][h][serp(w)] = sum_j ycat[b][j][l] * W_out[c][j]
__global__ void k_gemm_out(const float* __restrict__ ycat,
                           const float* __restrict__ Wout,
                           float* __restrict__ out) {
  const int lane = threadIdx.x;
  const int ty   = threadIdx.y;
  const int l    = blockIdx.x * 64 + lane;
  const int c0   = blockIdx.y * 16 + ty * 4;
  const int b    = blockIdx.z;
  const float* yb = ycat + ((size_t)b * DI) * L + l;
  const float* w0 = Wout + (size_t)(c0 + 0) * DI;
  const float* w1 = Wout + (size_t)(c0 + 1) * DI;
  const float* w2 = Wout + (size_t)(c0 + 2) * DI;
  const float* w3 = Wout + (size_t)(c0 + 3) * DI;
  float a0 = 0.f, a1 = 0.f, a2 = 0.f, a3 = 0.f;
#pragma unroll 8
  for (int j = 0; j < DI; ++j) {
    float yv = yb[(size_t)j * L];
    a0 = fmaf(w0[j], yv, a0);
    a1 = fmaf(w1[j], yv, a1);
    a2 = fmaf(w2[j], yv, a2);
    a3 = fmaf(w3[j], yv, a3);
  }
  const int h = l >> 5, w = l & 31;
  const int wsp = (h & 1) ? (31 - w) : w;          // serpentine write
  float* ob = out + ((size_t)b * DM) * L + h * 32 + wsp;
  ob[(size_t)(c0 + 0) * L] = a0;
  ob[(size_t)(c0 + 1) * L] = a1;
  ob[(size_t)(c0 + 2) * L] = a2;
  ob[(size_t)(c0 + 3) * L] = a3;
}

// ---------------------------------------------------------------------------
extern "C" void kernel_launch(void* const* d_in, const int* in_sizes, int n_in,
                              void* d_out, int out_size, void* d_ws, size_t ws_size,
                              hipStream_t stream) {
  const float* hid  = (const float*)d_in[0];
  const float* Win  = (const float*)d_in[1];
  const float* cwx  = (const float*)d_in[2];
  const float* cwz  = (const float*)d_in[3];
  const float* Wx   = (const float*)d_in[4];
  const float* Wdt  = (const float*)d_in[5];
  const float* bdt  = (const float*)d_in[6];
  const float* Alog = (const float*)d_in[7];
  const float* Dp   = (const float*)d_in[8];
  const float* Wout = (const float*)d_in[9];
  float* out = (float*)d_out;

  float* ws    = (float*)d_ws;
  float* xz    = ws;                          // NB*DI*L   = 3,145,728
  float* u     = xz   + (size_t)NB * DI * L;  // NB*DH*L   = 1,572,864
  float* ycat  = u    + (size_t)NB * DH * L;  // NB*DI*L   = 3,145,728
  float* xdbl  = ycat + (size_t)NB * DI * L;  // NB*L*XR   = 2,195,456
  float* delta = xdbl + (size_t)NB * L * XR;  // NB*DH*L   = 1,572,864

  k_gemm_in  <<<dim3(L / 64, DI / 16, NB), dim3(64, 4), 0, stream>>>(hid, Win, xz);
  k_conv_silu<<<dim3(2 * NB * DH * L / 256), dim3(256), 0, stream>>>(xz, cwx, cwz, u, ycat);
  k_gemm_xproj<<<dim3(L / 64, (XR + 15) / 16, NB), dim3(64, 4), 0, stream>>>(u, Wx, xdbl);
  k_delta    <<<dim3(NB * DH * L / 256), dim3(256), 0, stream>>>(xdbl, Wdt, bdt, delta);
  k_scan     <<<dim3(NB * DH), dim3(64), 0, stream>>>(xdbl, delta, u, Alog, Dp, ycat);
  k_gemm_out <<<dim3(L / 64, DM / 16, NB), dim3(64, 4), 0, stream>>>(ycat, Wout, out);
}

// Round 2
// 387.299 us; speedup vs baseline: 1.8885x; 1.8885x over previous
//
#include <hip/hip_runtime.h>
#include <math.h>

#define NB  8     // batch
#define DM  192   // D_MODEL
#define DH  192   // D_HALF
#define DI  384   // D_INNER
#define DS  128   // D_STATE
#define DTR 12    // DT_RANK
#define XR  268   // DT_RANK + 2*D_STATE
#define L   1024  // H*W
#define NC  16    // scan chunks
#define CL  64    // chunk length

// ---------------------------------------------------------------------------
// xz[b][j][l] = sum_c serp(hid)[b][c][l] * W_in[j][c]
__global__ void k_gemm_in(const float* __restrict__ hid,
                          const float* __restrict__ Win,
                          float* __restrict__ xz) {
  const int lane = threadIdx.x;          // 0..63
  const int ty   = threadIdx.y;          // 0..3
  const int l    = blockIdx.x * 64 + lane;
  const int j0   = blockIdx.y * 16 + ty * 4;
  const int b    = blockIdx.z;
  const int h = l >> 5, w = l & 31;
  const int wsp = (h & 1) ? (31 - w) : w;          // serpentine read
  const float* hb = hid + ((size_t)b * DM) * L + h * 32 + wsp;
  const float* w0 = Win + (size_t)(j0 + 0) * DM;
  const float* w1 = Win + (size_t)(j0 + 1) * DM;
  const float* w2 = Win + (size_t)(j0 + 2) * DM;
  const float* w3 = Win + (size_t)(j0 + 3) * DM;
  float a0 = 0.f, a1 = 0.f, a2 = 0.f, a3 = 0.f;
#pragma unroll 8
  for (int c = 0; c < DM; ++c) {
    float xv = hb[(size_t)c * L];
    a0 = fmaf(w0[c], xv, a0);
    a1 = fmaf(w1[c], xv, a1);
    a2 = fmaf(w2[c], xv, a2);
    a3 = fmaf(w3[c], xv, a3);
  }
  float* o = xz + ((size_t)b * DI + j0) * L + l;
  o[0]     = a0;
  o[L]     = a1;
  o[2 * L] = a2;
  o[3 * L] = a3;
}

// ---------------------------------------------------------------------------
__global__ void k_conv_silu(const float* __restrict__ xz,
                            const float* __restrict__ cwx,
                            const float* __restrict__ cwz,
                            float* __restrict__ u,
                            float* __restrict__ ycat) {
  int idx = blockIdx.x * blockDim.x + threadIdx.x;
  const int per = NB * DH * L;
  int part = idx / per;
  int rem  = idx - part * per;
  int l  = rem & (L - 1);
  int bd = rem >> 10;          // b*DH + d
  int d  = bd % DH;
  int b  = bd / DH;
  const float* cw = (part ? cwz : cwx) + d * 4;
  float w0 = cw[0], w1 = cw[1], w2 = cw[2], w3 = cw[3];
  const float* src = xz + ((size_t)b * DI + (part ? DH + d : d)) * L;
  float s = w3 * src[l];
  if (l >= 1) s = fmaf(w2, src[l - 1], s);
  if (l >= 2) s = fmaf(w1, src[l - 2], s);
  if (l >= 3) s = fmaf(w0, src[l - 3], s);
  float y = s / (1.f + __expf(-s));    // silu
  if (part) ycat[((size_t)b * DI + DH + d) * L + l] = y;
  else      u[(size_t)bd * L + l] = y;
}

// ---------------------------------------------------------------------------
// x_dbl[b][l][r] = sum_d u[b][d][l] * W_xproj[r][d]
__global__ void k_gemm_xproj(const float* __restrict__ u,
                             const float* __restrict__ Wx,
                             float* __restrict__ xdbl) {
  const int lane = threadIdx.x;
  const int ty   = threadIdx.y;
  const int l    = blockIdx.x * 64 + lane;
  const int r0   = blockIdx.y * 16 + ty * 4;
  const int b    = blockIdx.z;
  const float* ub = u + ((size_t)b * DH) * L + l;
  const int rr0 = min(r0 + 0, XR - 1);
  const int rr1 = min(r0 + 1, XR - 1);
  const int rr2 = min(r0 + 2, XR - 1);
  const int rr3 = min(r0 + 3, XR - 1);
  const float* w0 = Wx + (size_t)rr0 * DH;
  const float* w1 = Wx + (size_t)rr1 * DH;
  const float* w2 = Wx + (size_t)rr2 * DH;
  const float* w3 = Wx + (size_t)rr3 * DH;
  float a0 = 0.f, a1 = 0.f, a2 = 0.f, a3 = 0.f;
#pragma unroll 8
  for (int c = 0; c < DH; ++c) {
    float xv = ub[(size_t)c * L];
    a0 = fmaf(w0[c], xv, a0);
    a1 = fmaf(w1[c], xv, a1);
    a2 = fmaf(w2[c], xv, a2);
    a3 = fmaf(w3[c], xv, a3);
  }
  float* o = xdbl + ((size_t)b * L + l) * XR;
  if (r0 + 0 < XR) o[r0 + 0] = a0;
  if (r0 + 1 < XR) o[r0 + 1] = a1;
  if (r0 + 2 < XR) o[r0 + 2] = a2;
  if (r0 + 3 < XR) o[r0 + 3] = a3;
}

// ---------------------------------------------------------------------------
// delta[b][d][l] = softplus( W_dt . x_dbl + 2*b_dt[d] )  (ref adds b_dt twice)
__global__ void k_delta(const float* __restrict__ xdbl,
                        const float* __restrict__ Wdt,
                        const float* __restrict__ bdt,
                        float* __restrict__ delta) {
  int idx = blockIdx.x * blockDim.x + threadIdx.x;  // (b*DH+d)*L + l
  int l  = idx & (L - 1);
  int bd = idx >> 10;
  int d  = bd % DH;
  int b  = bd / DH;
  const float* xd = xdbl + ((size_t)b * L + l) * XR;
  const float* wd = Wdt + d * DTR;
  float s = 2.f * bdt[d];
#pragma unroll
  for (int r = 0; r < DTR; ++r) s = fmaf(wd[r], xd[r], s);
  float dl = (s > 20.f) ? s : log1pf(__expf(s));
  delta[(size_t)idx] = dl;
}

// ---------------------------------------------------------------------------
// Chunked scan, pass 1: per (b,d,chunk) wave, recurrence with h_in = 0.
// Stores partial state hp and decay product ap per state.
// layout: hpart/apart[(bd*NC + c)*128 + s*64 + lane]
__global__ void __launch_bounds__(256) k_scan1(const float* __restrict__ xdbl,
                                               const float* __restrict__ delta,
                                               const float* __restrict__ u,
                                               const float* __restrict__ Alog,
                                               float* __restrict__ hpart,
                                               float* __restrict__ apart) {
  const int lane = threadIdx.x & 63;
  const int wv   = threadIdx.x >> 6;
  const int d    = blockIdx.x * 4 + wv;
  const int c    = blockIdx.y;
  const int b    = blockIdx.z;
  const int bd   = b * DH + d;
  const float a1 = -__expf(Alog[d * DS + lane]) * 1.44269504f;
  const float a2 = -__expf(Alog[d * DS + 64 + lane]) * 1.44269504f;
  const float* xrow = xdbl + ((size_t)b * L + c * CL) * XR;
  const float* drow = delta + (size_t)bd * L + c * CL;
  const float* urow = u + (size_t)bd * L + c * CL;
  float h1 = 0.f, h2 = 0.f, ap1 = 1.f, ap2 = 1.f;
#pragma unroll 8
  for (int t = 0; t < CL; ++t) {
    const float* xd = xrow + (size_t)t * XR;
    float B1 = xd[DTR + lane];
    float B2 = xd[DTR + 64 + lane];
    float dt = drow[t], ut = urow[t];
    float e1 = __builtin_amdgcn_exp2f(dt * a1);
    float e2 = __builtin_amdgcn_exp2f(dt * a2);
    float du = dt * ut;
    h1 = fmaf(e1, h1, du * B1);
    h2 = fmaf(e2, h2, du * B2);
    ap1 *= e1;
    ap2 *= e2;
  }
  size_t o = (size_t)bd * (NC * 128) + c * 128 + lane;
  hpart[o] = h1;  hpart[o + 64] = h2;
  apart[o] = ap1; apart[o + 64] = ap2;
}

// ---------------------------------------------------------------------------
// pass 2: serial combine over the 16 chunks; overwrites hpart with the
// TRUE incoming state h_in of each chunk (in-place).
__global__ void __launch_bounds__(64) k_scan2(float* __restrict__ hpart,
                                              const float* __restrict__ apart) {
  const int bd   = blockIdx.x;
  const int lane = threadIdx.x;
  float H1 = 0.f, H2 = 0.f;
  size_t base = (size_t)bd * (NC * 128) + lane;
  for (int c = 0; c < NC; ++c) {
    size_t o = base + c * 128;
    float hp1 = hpart[o], hp2 = hpart[o + 64];
    float ap1 = apart[o], ap2 = apart[o + 64];
    hpart[o] = H1; hpart[o + 64] = H2;
    H1 = fmaf(ap1, H1, hp1);
    H2 = fmaf(ap2, H2, hp2);
  }
}

// ---------------------------------------------------------------------------
// pass 3: recompute each chunk from its true h_in; emit y.
// Per-step cross-lane reduce replaced by LDS transpose-reduce every 16 steps.
__global__ void __launch_bounds__(256) k_scan3(const float* __restrict__ xdbl,
                                               const float* __restrict__ delta,
                                               const float* __restrict__ u,
                                               const float* __restrict__ Alog,
                                               const float* __restrict__ Dp,
                                               const float* __restrict__ hin,
                                               float* __restrict__ ycat) {
  __shared__ float pbuf[4][16][66];
  const int lane = threadIdx.x & 63;
  const int wv   = threadIdx.x >> 6;
  const int d    = blockIdx.x * 4 + wv;
  const int c    = blockIdx.y;
  const int b    = blockIdx.z;
  const int bd   = b * DH + d;
  const float a1 = -__expf(Alog[d * DS + lane]) * 1.44269504f;
  const float a2 = -__expf(Alog[d * DS + 64 + lane]) * 1.44269504f;
  const float Dd = Dp[d];
  const float* xrow = xdbl + ((size_t)b * L + c * CL) * XR;
  const float* drow = delta + (size_t)bd * L + c * CL;
  const float* urow = u + (size_t)bd * L + c * CL;
  float* yrow = ycat + ((size_t)b * DI + d) * L + c * CL;
  size_t o = (size_t)bd * (NC * 128) + c * 128 + lane;
  float h1 = hin[o], h2 = hin[o + 64];
  const int tl = lane & 15, pp = lane >> 4;
  for (int t16 = 0; t16 < 4; ++t16) {
#pragma unroll
    for (int i = 0; i < 16; ++i) {
      int t = t16 * 16 + i;
      const float* xd = xrow + (size_t)t * XR;
      float B1 = xd[DTR + lane];
      float B2 = xd[DTR + 64 + lane];
      float C1 = xd[DTR + DS + lane];
      float C2 = xd[DTR + DS + 64 + lane];
      float dt = drow[t], ut = urow[t];
      float e1 = __builtin_amdgcn_exp2f(dt * a1);
      float e2 = __builtin_amdgcn_exp2f(dt * a2);
      float du = dt * ut;
      h1 = fmaf(e1, h1, du * B1);
      h2 = fmaf(e2, h2, du * B2);
      pbuf[wv][i][lane] = fmaf(h2, C2, h1 * C1);
    }
    float s = 0.f;
#pragma unroll
    for (int i = 0; i < 16; ++i) s += pbuf[wv][tl][pp * 16 + i];
    s += __shfl_xor(s, 16, 64);
    s += __shfl_xor(s, 32, 64);
    float uo = urow[t16 * 16 + tl];
    if (lane < 16) yrow[t16 * 16 + tl] = fmaf(Dd, uo, s);
  }
}

// ---------------------------------------------------------------------------
// fallback serial scan (used only if ws too small for chunked buffers)
__global__ void __launch_bounds__(64) k_scan(const float* __restrict__ xdbl,
                                             const float* __restrict__ delta,
                                             const float* __restrict__ u,
                                             const float* __restrict__ Alog,
                                             const float* __restrict__ Dp,
                                             float* __restrict__ ycat) {
  const int bd   = blockIdx.x;
  const int b    = bd / DH;
  const int d    = bd % DH;
  const int lane = threadIdx.x;
  const float a1 = -__expf(Alog[d * DS + lane]);
  const float a2 = -__expf(Alog[d * DS + 64 + lane]);
  const float* xrow = xdbl + (size_t)b * L * XR;
  const float* drow = delta + (size_t)bd * L;
  const float* urow = u + (size_t)bd * L;
  const float Dd = Dp[d];
  float* yrow = ycat + ((size_t)b * DI + d) * L;
  float h1 = 0.f, h2 = 0.f;
  for (int t = 0; t < L; ++t) {
    const float* xd = xrow + (size_t)t * XR;
    float Bv1 = xd[DTR + lane];
    float Bv2 = xd[DTR + 64 + lane];
    float Cv1 = xd[DTR + DS + lane];
    float Cv2 = xd[DTR + DS + 64 + lane];
    float dt = drow[t];
    float ut = urow[t];
    float du = dt * ut;
    h1 = fmaf(__expf(dt * a1), h1, du * Bv1);
    h2 = fmaf(__expf(dt * a2), h2, du * Bv2);
    float p = fmaf(h2, Cv2, h1 * Cv1);
#pragma unroll
    for (int m = 32; m; m >>= 1) p += __shfl_xor(p, m, 64);
    if (lane == 0) yrow[t] = fmaf(Dd, ut, p);
  }
}

// ---------------------------------------------------------------------------
// out[b][c][h][serp(w)] = sum_j ycat[b][j][l] * W_out[c][j]
__global__ void k_gemm_out(const float* __restrict__ ycat,
                           const float* __restrict__ Wout,
                           float* __restrict__ out) {
  const int lane = threadIdx.x;
  const int ty   = threadIdx.y;
  const int l    = blockIdx.x * 64 + lane;
  const int c0   = blockIdx.y * 16 + ty * 4;
  const int b    = blockIdx.z;
  const float* yb = ycat + ((size_t)b * DI) * L + l;
  const float* w0 = Wout + (size_t)(c0 + 0) * DI;
  const float* w1 = Wout + (size_t)(c0 + 1) * DI;
  const float* w2 = Wout + (size_t)(c0 + 2) * DI;
  const float* w3 = Wout + (size_t)(c0 + 3) * DI;
  float a0 = 0.f, a1 = 0.f, a2 = 0.f, a3 = 0.f;
#pragma unroll 8
  for (int j = 0; j < DI; ++j) {
    float yv = yb[(size_t)j * L];
    a0 = fmaf(w0[j], yv, a0);
    a1 = fmaf(w1[j], yv, a1);
    a2 = fmaf(w2[j], yv, a2);
    a3 = fmaf(w3[j], yv, a3);
  }
  const int h = l >> 5, w = l & 31;
  const int wsp = (h & 1) ? (31 - w) : w;          // serpentine write
  float* ob = out + ((size_t)b * DM) * L + h * 32 + wsp;
  ob[(size_t)(c0 + 0) * L] = a0;
  ob[(size_t)(c0 + 1) * L] = a1;
  ob[(size_t)(c0 + 2) * L] = a2;
  ob[(size_t)(c0 + 3) * L] = a3;
}

// ---------------------------------------------------------------------------
extern "C" void kernel_launch(void* const* d_in, const int* in_sizes, int n_in,
                              void* d_out, int out_size, void* d_ws, size_t ws_size,
                              hipStream_t stream) {
  const float* hid  = (const float*)d_in[0];
  const float* Win  = (const float*)d_in[1];
  const float* cwx  = (const float*)d_in[2];
  const float* cwz  = (const float*)d_in[3];
  const float* Wx   = (const float*)d_in[4];
  const float* Wdt  = (const float*)d_in[5];
  const float* bdt  = (const float*)d_in[6];
  const float* Alog = (const float*)d_in[7];
  const float* Dp   = (const float*)d_in[8];
  const float* Wout = (const float*)d_in[9];
  float* out = (float*)d_out;

  float* ws    = (float*)d_ws;
  float* xz    = ws;                          // NB*DI*L   = 3,145,728
  float* u     = xz   + (size_t)NB * DI * L;  // NB*DH*L   = 1,572,864
  float* ycat  = u    + (size_t)NB * DH * L;  // NB*DI*L   = 3,145,728
  float* xdbl  = ycat + (size_t)NB * DI * L;  // NB*L*XR   = 2,195,456
  float* delta = xdbl + (size_t)NB * L * XR;  // NB*DH*L   = 1,572,864
  float* apart = delta + (size_t)NB * DH * L; // NB*DH*NC*128 = 3,145,728
  float* hpart = xz;                          // aliases xz (dead after conv)

  const size_t need = ((size_t)NB * DI * L * 2 + (size_t)NB * DH * L * 2 +
                       (size_t)NB * L * XR + (size_t)NB * DH * NC * 128) * 4;

  k_gemm_in  <<<dim3(L / 64, DI / 16, NB), dim3(64, 4), 0, stream>>>(hid, Win, xz);
  k_conv_silu<<<dim3(2 * NB * DH * L / 256), dim3(256), 0, stream>>>(xz, cwx, cwz, u, ycat);
  k_gemm_xproj<<<dim3(L / 64, (XR + 15) / 16, NB), dim3(64, 4), 0, stream>>>(u, Wx, xdbl);
  k_delta    <<<dim3(NB * DH * L / 256), dim3(256), 0, stream>>>(xdbl, Wdt, bdt, delta);

  if (ws_size >= need) {
    k_scan1<<<dim3(DH / 4, NC, NB), dim3(256), 0, stream>>>(xdbl, delta, u, Alog, hpart, apart);
    k_scan2<<<dim3(NB * DH), dim3(64), 0, stream>>>(hpart, apart);
    k_scan3<<<dim3(DH / 4, NC, NB), dim3(256), 0, stream>>>(xdbl, delta, u, Alog, Dp, hpart, ycat);
  } else {
    k_scan<<<dim3(NB * DH), dim3(64), 0, stream>>>(xdbl, delta, u, Alog, Dp, ycat);
  }

  k_gemm_out <<<dim3(L / 64, DM / 16, NB), dim3(64, 4), 0, stream>>>(ycat, Wout, out);
}

// Round 3
// 233.990 us; speedup vs baseline: 3.1259x; 1.6552x over previous
//
#include <hip/hip_runtime.h>
#include <math.h>

#define NB  8     // batch
#define DM  192   // D_MODEL
#define DH  192   // D_HALF
#define DI  384   // D_INNER
#define DS  128   // D_STATE
#define DTR 12    // DT_RANK
#define XR  268   // DT_RANK + 2*D_STATE
#define L   1024  // H*W
#define NC  16    // scan chunks
#define CL  64    // chunk length
#define NWX 320   // padded row length for transposed W_xproj

// ---------------------------------------------------------------------------
// Fused weight transpose: W[N][K] row-major -> Wt[K][NW] k-major (zero pad).
// z=0: W_in 384x192 -> [192][384]; z=1: W_xproj 268x192 -> [192][320];
// z=2: W_out 192x384 -> [384][192]
__global__ void k_wt_all(const float* __restrict__ Win,
                         const float* __restrict__ Wx,
                         const float* __restrict__ Wout,
                         float* __restrict__ wt_in,
                         float* __restrict__ wt_x,
                         float* __restrict__ wt_out) {
  const int j = blockIdx.x * 256 + threadIdx.x;
  const int k = blockIdx.y;
  const int z = blockIdx.z;
  if (z == 0) {
    if (k < 192 && j < 384) wt_in[(size_t)k * 384 + j] = Win[(size_t)j * 192 + k];
  } else if (z == 1) {
    if (k < 192 && j < NWX) wt_x[(size_t)k * NWX + j] = (j < XR) ? Wx[(size_t)j * 192 + k] : 0.f;
  } else {
    if (k < 384 && j < 192) wt_out[(size_t)k * 192 + j] = Wout[(size_t)j * 384 + k];
  }
}

// ---------------------------------------------------------------------------
// High-density f32 GEMM: Out[n][l] = sum_k A[k][l] * Wt[k][n]
// Block: 256 thr = 4 waves; tile 64 l x 64 n; wave owns 16 n (wave-uniform ->
// weights come through the scalar pipe). A staged in LDS (8 KB), 1 ds_read_b32
// + 16 FMA per k per thread.
// SERP_IN: serpentine-remap the A column. OMODE 0: Out[n][l]; 1: Out[l][n]
// (guarded to n<XR); 2: Out[n][serp(l)].
template<int K, int N, int NW, int SERP_IN, int OMODE>
__global__ __launch_bounds__(256) void k_gemm(const float* __restrict__ A,
                                              const float* __restrict__ Wt,
                                              float* __restrict__ Out) {
  __shared__ float At[32][64];
  const int lane = threadIdx.x & 63;
  const int wv   = threadIdx.x >> 6;
  const int l    = blockIdx.x * 64 + lane;
  const int n0   = __builtin_amdgcn_readfirstlane(blockIdx.y * 64 + wv * 16);
  const int b    = blockIdx.z;
  int lg = l;
  if (SERP_IN || OMODE == 2) {
    int h = l >> 5, w = l & 31;
    lg = h * 32 + ((h & 1) ? (31 - w) : w);
  }
  const float* Ab = A + (size_t)b * K * L + (SERP_IN ? lg : l);
  float acc[16];
#pragma unroll
  for (int i = 0; i < 16; ++i) acc[i] = 0.f;

  for (int k0 = 0; k0 < K; k0 += 32) {
#pragma unroll
    for (int i = 0; i < 8; ++i) {
      int kr = wv * 8 + i;
      At[kr][lane] = Ab[(size_t)(k0 + kr) * L];
    }
    __syncthreads();
#pragma unroll
    for (int kk = 0; kk < 32; ++kk) {
      float a = At[kk][lane];
      const float* wr = Wt + (size_t)(k0 + kk) * NW + n0;
#pragma unroll
      for (int i = 0; i < 16; ++i) acc[i] = fmaf(wr[i], a, acc[i]);
    }
    __syncthreads();
  }

  if (OMODE == 0) {
    float* o = Out + ((size_t)b * N + n0) * L + l;
#pragma unroll
    for (int i = 0; i < 16; ++i) o[(size_t)i * L] = acc[i];
  } else if (OMODE == 1) {
    float* o = Out + ((size_t)b * L + l) * XR;
#pragma unroll
    for (int i = 0; i < 16; i += 4) {
      if (n0 + i + 4 <= XR)
        *(float4*)(o + n0 + i) = make_float4(acc[i], acc[i + 1], acc[i + 2], acc[i + 3]);
    }
  } else {
    float* o = Out + ((size_t)b * N + n0) * L + lg;
#pragma unroll
    for (int i = 0; i < 16; ++i) o[(size_t)i * L] = acc[i];
  }
}

// ---------------------------------------------------------------------------
// causal depthwise conv (k=4) + SiLU, 4 l per thread (float4).
__global__ void k_conv_silu(const float* __restrict__ xz,
                            const float* __restrict__ cwx,
                            const float* __restrict__ cwz,
                            float* __restrict__ u,
                            float* __restrict__ ycat) {
  int idx = blockIdx.x * blockDim.x + threadIdx.x;
  const int per = NB * DH * (L / 4);
  int part = idx / per;
  int rem  = idx - part * per;
  int l4 = (rem & (L / 4 - 1)) * 4;
  int bd = rem >> 8;           // b*DH + d
  int d  = bd % DH;
  int b  = bd / DH;
  const float* cw = (part ? cwz : cwx) + d * 4;
  float w0 = cw[0], w1 = cw[1], w2 = cw[2], w3 = cw[3];
  const float* src = xz + ((size_t)b * DI + (part ? DH + d : d)) * L;
  float4 cur = *(const float4*)(src + l4);
  float pm3 = 0.f, pm2 = 0.f, pm1 = 0.f;
  if (l4 >= 4) {
    float4 p = *(const float4*)(src + l4 - 4);
    pm3 = p.y; pm2 = p.z; pm1 = p.w;
  }
  float s0 = fmaf(w3, cur.x, fmaf(w2, pm1,   fmaf(w1, pm2,   w0 * pm3)));
  float s1 = fmaf(w3, cur.y, fmaf(w2, cur.x, fmaf(w1, pm1,   w0 * pm2)));
  float s2 = fmaf(w3, cur.z, fmaf(w2, cur.y, fmaf(w1, cur.x, w0 * pm1)));
  float s3 = fmaf(w3, cur.w, fmaf(w2, cur.z, fmaf(w1, cur.y, w0 * cur.x)));
  float4 y;
  y.x = s0 / (1.f + __expf(-s0));
  y.y = s1 / (1.f + __expf(-s1));
  y.z = s2 / (1.f + __expf(-s2));
  y.w = s3 / (1.f + __expf(-s3));
  float* dst = part ? (ycat + ((size_t)b * DI + DH + d) * L + l4)
                    : (u + (size_t)bd * L + l4);
  *(float4*)dst = y;
}

// ---------------------------------------------------------------------------
// delta[b][d][l] = softplus( W_dt . x_dbl + 2*b_dt[d] )  (ref adds b_dt twice)
__global__ void k_delta(const float* __restrict__ xdbl,
                        const float* __restrict__ Wdt,
                        const float* __restrict__ bdt,
                        float* __restrict__ delta) {
  int idx = blockIdx.x * blockDim.x + threadIdx.x;  // (b*DH+d)*L + l
  int l  = idx & (L - 1);
  int bd = idx >> 10;
  int d  = bd % DH;
  int b  = bd / DH;
  const float* xd = xdbl + ((size_t)b * L + l) * XR;
  const float* wd = Wdt + d * DTR;
  float s = 2.f * bdt[d];
#pragma unroll
  for (int r = 0; r < DTR; ++r) s = fmaf(wd[r], xd[r], s);
  float dl = (s > 20.f) ? s : __logf(1.f + __expf(s));
  delta[(size_t)idx] = dl;
}

// ---------------------------------------------------------------------------
// Chunked scan, pass 1: per (b,d,chunk) wave, recurrence with h_in = 0.
__global__ void __launch_bounds__(256) k_scan1(const float* __restrict__ xdbl,
                                               const float* __restrict__ delta,
                                               const float* __restrict__ u,
                                               const float* __restrict__ Alog,
                                               float* __restrict__ hpart,
                                               float* __restrict__ apart) {
  const int lane = threadIdx.x & 63;
  const int wv   = threadIdx.x >> 6;
  const int d    = blockIdx.x * 4 + wv;
  const int c    = blockIdx.y;
  const int b    = blockIdx.z;
  const int bd   = b * DH + d;
  const float a1 = -__expf(Alog[d * DS + lane]) * 1.44269504f;
  const float a2 = -__expf(Alog[d * DS + 64 + lane]) * 1.44269504f;
  const float* xrow = xdbl + ((size_t)b * L + c * CL) * XR;
  const float* drow = delta + (size_t)bd * L + c * CL;
  const float* urow = u + (size_t)bd * L + c * CL;
  float h1 = 0.f, h2 = 0.f, ap1 = 1.f, ap2 = 1.f;
#pragma unroll 8
  for (int t = 0; t < CL; ++t) {
    const float* xd = xrow + (size_t)t * XR;
    float B1 = xd[DTR + lane];
    float B2 = xd[DTR + 64 + lane];
    float dt = drow[t], ut = urow[t];
    float e1 = __builtin_amdgcn_exp2f(dt * a1);
    float e2 = __builtin_amdgcn_exp2f(dt * a2);
    float du = dt * ut;
    h1 = fmaf(e1, h1, du * B1);
    h2 = fmaf(e2, h2, du * B2);
    ap1 *= e1;
    ap2 *= e2;
  }
  size_t o = (size_t)bd * (NC * 128) + c * 128 + lane;
  hpart[o] = h1;  hpart[o + 64] = h2;
  apart[o] = ap1; apart[o + 64] = ap2;
}

// ---------------------------------------------------------------------------
// pass 2: serial combine; overwrites hpart with true incoming state per chunk.
__global__ void __launch_bounds__(64) k_scan2(float* __restrict__ hpart,
                                              const float* __restrict__ apart) {
  const int bd   = blockIdx.x;
  const int lane = threadIdx.x;
  float H1 = 0.f, H2 = 0.f;
  size_t base = (size_t)bd * (NC * 128) + lane;
  for (int c = 0; c < NC; ++c) {
    size_t o = base + c * 128;
    float hp1 = hpart[o], hp2 = hpart[o + 64];
    float ap1 = apart[o], ap2 = apart[o + 64];
    hpart[o] = H1; hpart[o + 64] = H2;
    H1 = fmaf(ap1, H1, hp1);
    H2 = fmaf(ap2, H2, hp2);
  }
}

// ---------------------------------------------------------------------------
// pass 3: recompute each chunk from its true h_in; emit y.
__global__ void __launch_bounds__(256) k_scan3(const float* __restrict__ xdbl,
                                               const float* __restrict__ delta,
                                               const float* __restrict__ u,
                                               const float* __restrict__ Alog,
                                               const float* __restrict__ Dp,
                                               const float* __restrict__ hin,
                                               float* __restrict__ ycat) {
  __shared__ float pbuf[4][16][66];
  const int lane = threadIdx.x & 63;
  const int wv   = threadIdx.x >> 6;
  const int d    = blockIdx.x * 4 + wv;
  const int c    = blockIdx.y;
  const int b    = blockIdx.z;
  const int bd   = b * DH + d;
  const float a1 = -__expf(Alog[d * DS + lane]) * 1.44269504f;
  const float a2 = -__expf(Alog[d * DS + 64 + lane]) * 1.44269504f;
  const float Dd = Dp[d];
  const float* xrow = xdbl + ((size_t)b * L + c * CL) * XR;
  const float* drow = delta + (size_t)bd * L + c * CL;
  const float* urow = u + (size_t)bd * L + c * CL;
  float* yrow = ycat + ((size_t)b * DI + d) * L + c * CL;
  size_t o = (size_t)bd * (NC * 128) + c * 128 + lane;
  float h1 = hin[o], h2 = hin[o + 64];
  const int tl = lane & 15, pp = lane >> 4;
  for (int t16 = 0; t16 < 4; ++t16) {
#pragma unroll
    for (int i = 0; i < 16; ++i) {
      int t = t16 * 16 + i;
      const float* xd = xrow + (size_t)t * XR;
      float B1 = xd[DTR + lane];
      float B2 = xd[DTR + 64 + lane];
      float C1 = xd[DTR + DS + lane];
      float C2 = xd[DTR + DS + 64 + lane];
      float dt = drow[t], ut = urow[t];
      float e1 = __builtin_amdgcn_exp2f(dt * a1);
      float e2 = __builtin_amdgcn_exp2f(dt * a2);
      float du = dt * ut;
      h1 = fmaf(e1, h1, du * B1);
      h2 = fmaf(e2, h2, du * B2);
      pbuf[wv][i][lane] = fmaf(h2, C2, h1 * C1);
    }
    float s = 0.f;
#pragma unroll
    for (int i = 0; i < 16; ++i) s += pbuf[wv][tl][pp * 16 + i];
    s += __shfl_xor(s, 16, 64);
    s += __shfl_xor(s, 32, 64);
    float uo = urow[t16 * 16 + tl];
    if (lane < 16) yrow[t16 * 16 + tl] = fmaf(Dd, uo, s);
  }
}

// ---------------------------------------------------------------------------
// fallback serial scan (used only if ws too small for chunked buffers)
__global__ void __launch_bounds__(64) k_scan(const float* __restrict__ xdbl,
                                             const float* __restrict__ delta,
                                             const float* __restrict__ u,
                                             const float* __restrict__ Alog,
                                             const float* __restrict__ Dp,
                                             float* __restrict__ ycat) {
  const int bd   = blockIdx.x;
  const int b    = bd / DH;
  const int d    = bd % DH;
  const int lane = threadIdx.x;
  const float a1 = -__expf(Alog[d * DS + lane]);
  const float a2 = -__expf(Alog[d * DS + 64 + lane]);
  const float* xrow = xdbl + (size_t)b * L * XR;
  const float* drow = delta + (size_t)bd * L;
  const float* urow = u + (size_t)bd * L;
  const float Dd = Dp[d];
  float* yrow = ycat + ((size_t)b * DI + d) * L;
  float h1 = 0.f, h2 = 0.f;
  for (int t = 0; t < L; ++t) {
    const float* xd = xrow + (size_t)t * XR;
    float Bv1 = xd[DTR + lane];
    float Bv2 = xd[DTR + 64 + lane];
    float Cv1 = xd[DTR + DS + lane];
    float Cv2 = xd[DTR + DS + 64 + lane];
    float dt = drow[t];
    float ut = urow[t];
    float du = dt * ut;
    h1 = fmaf(__expf(dt * a1), h1, du * Bv1);
    h2 = fmaf(__expf(dt * a2), h2, du * Bv2);
    float p = fmaf(h2, Cv2, h1 * Cv1);
#pragma unroll
    for (int m = 32; m; m >>= 1) p += __shfl_xor(p, m, 64);
    if (lane == 0) yrow[t] = fmaf(Dd, ut, p);
  }
}

// ---------------------------------------------------------------------------
extern "C" void kernel_launch(void* const* d_in, const int* in_sizes, int n_in,
                              void* d_out, int out_size, void* d_ws, size_t ws_size,
                              hipStream_t stream) {
  const float* hid  = (const float*)d_in[0];
  const float* Win  = (const float*)d_in[1];
  const float* cwx  = (const float*)d_in[2];
  const float* cwz  = (const float*)d_in[3];
  const float* Wx   = (const float*)d_in[4];
  const float* Wdt  = (const float*)d_in[5];
  const float* bdt  = (const float*)d_in[6];
  const float* Alog = (const float*)d_in[7];
  const float* Dp   = (const float*)d_in[8];
  const float* Wout = (const float*)d_in[9];
  float* out = (float*)d_out;

  float* ws    = (float*)d_ws;
  float* xz    = ws;                          // NB*DI*L   = 3,145,728
  float* u     = xz   + (size_t)NB * DI * L;  // NB*DH*L   = 1,572,864
  float* ycat  = u    + (size_t)NB * DH * L;  // NB*DI*L   = 3,145,728
  float* xdbl  = ycat + (size_t)NB * DI * L;  // NB*L*XR   = 2,195,456
  float* delta = xdbl + (size_t)NB * L * XR;  // NB*DH*L   = 1,572,864
  float* apart = delta + (size_t)NB * DH * L; // NB*DH*NC*128 = 3,145,728
  float* wt_in = apart + (size_t)NB * DH * NC * 128;  // 192*384 = 73,728
  float* wt_x  = wt_in + (size_t)192 * 384;           // 192*320 = 61,440
  float* wt_out= wt_x  + (size_t)192 * NWX;           // 384*192 = 73,728
  float* hpart = xz;                          // aliases xz (dead after conv)

  const size_t need = ((size_t)NB * DI * L * 2 + (size_t)NB * DH * L * 2 +
                       (size_t)NB * L * XR + (size_t)NB * DH * NC * 128 +
                       (size_t)192 * 384 + (size_t)192 * NWX + (size_t)384 * 192) * 4;

  k_wt_all<<<dim3(2, 384, 3), dim3(256), 0, stream>>>(Win, Wx, Wout, wt_in, wt_x, wt_out);

  k_gemm<192, 384, 384, 1, 0><<<dim3(16, 6, NB), dim3(256), 0, stream>>>(hid, wt_in, xz);
  k_conv_silu<<<dim3(2 * NB * DH * (L / 4) / 256), dim3(256), 0, stream>>>(xz, cwx, cwz, u, ycat);
  k_gemm<192, XR, NWX, 0, 1><<<dim3(16, 5, NB), dim3(256), 0, stream>>>(u, wt_x, xdbl);
  k_delta<<<dim3(NB * DH * L / 256), dim3(256), 0, stream>>>(xdbl, Wdt, bdt, delta);

  if (ws_size >= need) {
    k_scan1<<<dim3(DH / 4, NC, NB), dim3(256), 0, stream>>>(xdbl, delta, u, Alog, hpart, apart);
    k_scan2<<<dim3(NB * DH), dim3(64), 0, stream>>>(hpart, apart);
    k_scan3<<<dim3(DH / 4, NC, NB), dim3(256), 0, stream>>>(xdbl, delta, u, Alog, Dp, hpart, ycat);
  } else {
    k_scan<<<dim3(NB * DH), dim3(64), 0, stream>>>(xdbl, delta, u, Alog, Dp, ycat);
  }

  k_gemm<384, 192, 192, 0, 2><<<dim3(16, 3, NB), dim3(256), 0, stream>>>(ycat, wt_out, out);
}